// Round 3
// baseline (130.592 us; speedup 1.0000x reference)
//
#include <hip/hip_runtime.h>
#include <hip/hip_bf16.h>

// CrossNetLayer: h = x @ W_enc + b_enc; then 4 cross layers
//   s = x_l . w_l (per row); x_l += x0 * s + b_l
// B = D = H = 1024, DEPTH = 4. fp32 in/out; GEMM internally f16 MFMA.
//
// R3: TWO kernels. prep = W transpose-cast only. fused = row-complete
// GEMM (block owns 16 full rows, barrier-free K-loop: A staged once in
// LDS, B fragments streamed global->VGPR from L2-resident Wt) + in-block
// crossnet epilogue. Kills the xh pass, the h round-trip, and one launch.

#define B_SZ 1024
#define D_SZ 1024
#define H_SZ 1024
#define DEPTH 4

typedef _Float16 half4_t __attribute__((ext_vector_type(4)));
typedef _Float16 half8_t __attribute__((ext_vector_type(8)));
typedef float floatx4_t __attribute__((ext_vector_type(4)));

// ---------------------------------------------------------------------------
// Kernel 1: prep. Transpose-convert W (fp32 [k][n]) -> Wt (f16 [n][k]).
// ---------------------------------------------------------------------------
__global__ __launch_bounds__(256) void prep_kernel(
        const float* __restrict__ W, _Float16* __restrict__ Wt) {
    const int b = blockIdx.x;
    const int t = threadIdx.x;
    __shared__ float S[64][65];        // +1 pad: transposed reads conflict-free
    const int k0 = (b >> 4) << 6;
    const int n0 = (b & 15) << 6;
#pragma unroll
    for (int i = 0; i < 4; ++i) {
        int idx = (i << 8) + t;
        int r = idx >> 4;              // k-local 0..63
        int c4 = idx & 15;             // float4 group along n
        float4 v = *(const float4*)(W + (size_t)(k0 + r) * H_SZ + n0 + (c4 << 2));
        S[r][(c4 << 2) + 0] = v.x;
        S[r][(c4 << 2) + 1] = v.y;
        S[r][(c4 << 2) + 2] = v.z;
        S[r][(c4 << 2) + 3] = v.w;
    }
    __syncthreads();
#pragma unroll
    for (int i = 0; i < 4; ++i) {
        int idx = (i << 8) + t;
        int n = idx >> 4;              // n-local 0..63
        int c4 = idx & 15;
        int k = c4 << 2;
        half4_t o;
        o.x = (_Float16)S[k + 0][n];
        o.y = (_Float16)S[k + 1][n];
        o.z = (_Float16)S[k + 2][n];
        o.w = (_Float16)S[k + 3][n];
        *(half4_t*)(Wt + (size_t)(n0 + n) * D_SZ + k0 + k) = o;
    }
}

// ---------------------------------------------------------------------------
// Kernel 2: fused GEMM + crossnet. 64 blocks x 512 thr. Block owns rows
// m0..m0+15 completely (N=1024, K=1024). Wave w owns cols [w*128,(w+1)*128).
// A: LDS (staged once, f32->f16 cast in-kernel). B: global->VGPR fragments
// from Wt (k-contiguous). No barriers in the K-loop -> deep vmcnt pipeline.
// ---------------------------------------------------------------------------
__global__ __launch_bounds__(512, 2) void fused_kernel(
        const float* __restrict__ x, const _Float16* __restrict__ Wt,
        const float* __restrict__ b_enc, const float* __restrict__ ws,
        const float* __restrict__ bs, float* __restrict__ out) {
    // A rows padded +8 halfs (16 B): frag-read bank pattern 2-way (free).
    __shared__ _Float16 Ash[16][1032];
    __shared__ float red[DEPTH][16][8];

    const int tid  = threadIdx.x;
    const int lane = tid & 63;
    const int w    = tid >> 6;         // wave 0..7
    const int m0   = blockIdx.x << 4;

    // ---- stage A: x[m0..m0+15][0..1023] f32 -> f16 LDS ----
    {
        const int r  = tid >> 5;               // row 0..15
        const int cb = (tid & 31) << 2;        // col base (float4 granular)
        const float* src = x + (size_t)(m0 + r) * D_SZ;
#pragma unroll
        for (int i = 0; i < 8; ++i) {
            int c = cb + (i << 7);             // lanes contiguous per instr
            float4 v = *(const float4*)(src + c);
            half4_t o;
            o.x = (_Float16)v.x; o.y = (_Float16)v.y;
            o.z = (_Float16)v.z; o.w = (_Float16)v.w;
            *(half4_t*)(&Ash[r][c]) = o;
        }
    }
    __syncthreads();   // the only pre-epilogue barrier

    // fragment geometry (16x16x32 f16): A[m=lane&15][k=q*8+j], B symmetric.
    const int cq = lane & 15;
    const int q  = lane >> 4;
    const _Float16* ap = &Ash[cq][q << 3];
    const _Float16* bp = Wt + (size_t)((w << 7) + cq) * D_SZ + (q << 3);

    floatx4_t acc[8];
#pragma unroll
    for (int t = 0; t < 8; ++t) acc[t] = (floatx4_t){0.f, 0.f, 0.f, 0.f};

#pragma unroll 2
    for (int kc = 0; kc < 32; ++kc) {
        half8_t af = *(const half8_t*)(ap + (kc << 5));
#pragma unroll
        for (int t = 0; t < 8; ++t) {
            half8_t bf = *(const half8_t*)(bp + t * (16 * D_SZ) + (kc << 5));
            acc[t] = __builtin_amdgcn_mfma_f32_16x16x32_f16(af, bf, acc[t], 0, 0, 0);
        }
    }

    // ---- crossnet epilogue, in-block ----
    // C/D: col = lane&15 (cq), local row = q*4 + reg.
    float be[8], wv[DEPTH][8], bv[DEPTH][8];
#pragma unroll
    for (int t = 0; t < 8; ++t) {
        int col = (w << 7) + (t << 4) + cq;
        be[t] = b_enc[col];
#pragma unroll
        for (int l = 0; l < DEPTH; ++l) {
            wv[l][t] = ws[l * H_SZ + col];
            bv[l][t] = bs[l * H_SZ + col];
        }
    }
    float x0[8][4], xl[8][4];
#pragma unroll
    for (int t = 0; t < 8; ++t)
#pragma unroll
        for (int r = 0; r < 4; ++r) {
            x0[t][r] = acc[t][r] + be[t];
            xl[t][r] = x0[t][r];
        }

    const int r0 = q << 2;   // local row base for this lane's regs
#pragma unroll
    for (int l = 0; l < DEPTH; ++l) {
        float p[4];
#pragma unroll
        for (int r = 0; r < 4; ++r) {
            p[r] = xl[0][r] * wv[l][0];
#pragma unroll
            for (int t = 1; t < 8; ++t) p[r] += xl[t][r] * wv[l][t];
        }
        // reduce across the 16 lanes of this q-group (cols of this wave)
#pragma unroll
        for (int off = 8; off > 0; off >>= 1)
#pragma unroll
            for (int r = 0; r < 4; ++r) p[r] += __shfl_down(p[r], off, 16);
        if (cq == 0)
#pragma unroll
            for (int r = 0; r < 4; ++r) red[l][r0 + r][w] = p[r];
        __syncthreads();   // per-layer slots -> one barrier per layer
        float s[4];
#pragma unroll
        for (int r = 0; r < 4; ++r) {
            float4 a = *(const float4*)&red[l][r0 + r][0];
            float4 b = *(const float4*)&red[l][r0 + r][4];
            s[r] = (a.x + a.y) + (a.z + a.w) + (b.x + b.y) + (b.z + b.w);
        }
#pragma unroll
        for (int t = 0; t < 8; ++t)
#pragma unroll
            for (int r = 0; r < 4; ++r)
                xl[t][r] += x0[t][r] * s[r] + bv[l][t];
    }

    // store final x_l
#pragma unroll
    for (int t = 0; t < 8; ++t) {
        int col = (w << 7) + (t << 4) + cq;
#pragma unroll
        for (int r = 0; r < 4; ++r)
            out[(size_t)(m0 + r0 + r) * H_SZ + col] = xl[t][r];
    }
}

extern "C" void kernel_launch(void* const* d_in, const int* in_sizes, int n_in,
                              void* d_out, int out_size, void* d_ws, size_t ws_size,
                              hipStream_t stream) {
    const float* x     = (const float*)d_in[0];
    const float* W_enc = (const float*)d_in[1];
    const float* b_enc = (const float*)d_in[2];
    const float* ws    = (const float*)d_in[3];
    const float* bs    = (const float*)d_in[4];
    float* out = (float*)d_out;

    _Float16* Wt = (_Float16*)d_ws;   // 2 MB

    prep_kernel<<<256, 256, 0, stream>>>(W_enc, Wt);
    fused_kernel<<<B_SZ / 16, 512, 0, stream>>>(x, Wt, b_enc, ws, bs, out);
}